// Round 2
// baseline (188.608 us; speedup 1.0000x reference)
//
#include <hip/hip_runtime.h>

#define B_ 64
#define L_ 512
#define H_ 512
#define CENTER 255

typedef float  f32x4  __attribute__((ext_vector_type(4)));
typedef _Float16 f16x8 __attribute__((ext_vector_type(8)));
typedef unsigned short u16x4 __attribute__((ext_vector_type(4)));
typedef unsigned short USH;

// ws layout (floats):
//   scores   [0,      32768)
//   dec_feat [32768,  65536)
//   cov_feat [65536,  98304)
//   flags    [98304,  98368)   int[64]: per-batch arrival counters (zeroed by pre)
//   Bpk     [360448, 491520)   ushort[512][512]: fp16(attn_w) bits (row-major n,k)

__device__ __forceinline__ float fast_tanh(float x) {
    float e = __expf(2.0f * x);
    return 1.0f - 2.0f * __builtin_amdgcn_rcpf(e + 1.0f);
}

// ================= pre: cov-direct (0..511) + conv_b/zeroing (512..639) + dec (640..895) =
__launch_bounds__(512)
__global__ void pre_kernel(const float* __restrict__ cvg_w, const float* __restrict__ cvg_b,
                           const float* __restrict__ coverage,
                           const float* __restrict__ aw, USH* __restrict__ bh16,
                           const float* __restrict__ hidden, const float* __restrict__ dec_w,
                           const float* __restrict__ dec_b,
                           float* __restrict__ dec_feat, float* __restrict__ cov_feat,
                           int* __restrict__ flags, float* __restrict__ out) {
    __shared__ float pool[34304];      // role A: wl[512] + cs[512][65]; role C: sbuf+pr
    const int bid = blockIdx.x, t = threadIdx.x;
    if (bid < 512) {
        float* wl = pool;                          // [512]
        float* cs = pool + 512;                    // [j][c] = [512][65]
        const int i = bid;
        wl[t] = cvg_w[((size_t)(i * L_ + t)) * H_ + CENTER];   // 1 scattered line/thread
        #pragma unroll 8
        for (int c = 0; c < 64; ++c)
            cs[t * 65 + c] = coverage[c * L_ + t];             // coalesced; write 2/bank
        __syncthreads();
        const int b = t >> 3, jg = t & 7;
        float sum = 0.f;
        #pragma unroll 8
        for (int jj = 0; jj < 64; ++jj) {
            int j = jg * 64 + ((jj + jg * 8) & 63);            // rotation: read 2/bank
            sum += cs[j * 65 + b] * wl[j];
        }
        sum += __shfl_xor(sum, 1, 64);
        sum += __shfl_xor(sum, 2, 64);
        sum += __shfl_xor(sum, 4, 64);
        if (jg == 0) cov_feat[b * L_ + i] = sum + cvg_b[i];
    } else if (bid < 640) {
        int i = (bid - 512) * 512 + t;             // float4 per thread
        float4 x = *(const float4*)&aw[(size_t)i * 4];
        float xs[4] = {x.x, x.y, x.z, x.w};
        u16x4 h;
        #pragma unroll
        for (int j = 0; j < 4; ++j)
            h[j] = __builtin_bit_cast(USH, (_Float16)xs[j]);
        *(u16x4*)&bh16[(size_t)i * 4] = h;
        if (bid < 576) out[(bid - 512) * 512 + t] = 0.f;       // zero context accumulators
        if (bid == 512 && t < 64) flags[t] = 0;                // zero arrival counters
    } else {
        float* sbuf = pool;                        // [512]
        float* pr   = pool + 512;                  // [512]
        const int blk = bid - 640, b = blk >> 2, qq = blk & 3;
        const int ol = t & 127, part = t >> 7;
        sbuf[t] = hidden[b * H_ + t];
        __syncthreads();
        const float* row  = dec_w + (size_t)(qq * 128 + ol) * H_ + part * 128;
        const float* hseg = sbuf + part * 128;
        float d0 = 0.f, d1 = 0.f, d2 = 0.f, d3 = 0.f;
        #pragma unroll
        for (int k = 0; k < 128; k += 16) {
            float4 w0 = *(const float4*)&row[k];
            float4 w1 = *(const float4*)&row[k + 4];
            float4 w2 = *(const float4*)&row[k + 8];
            float4 w3 = *(const float4*)&row[k + 12];
            d0 += w0.x * hseg[k]      + w0.y * hseg[k + 1]  + w0.z * hseg[k + 2]  + w0.w * hseg[k + 3];
            d1 += w1.x * hseg[k + 4]  + w1.y * hseg[k + 5]  + w1.z * hseg[k + 6]  + w1.w * hseg[k + 7];
            d2 += w2.x * hseg[k + 8]  + w2.y * hseg[k + 9]  + w2.z * hseg[k + 10] + w2.w * hseg[k + 11];
            d3 += w3.x * hseg[k + 12] + w3.y * hseg[k + 13] + w3.z * hseg[k + 14] + w3.w * hseg[k + 15];
        }
        pr[t] = d0 + d1 + d2 + d3;
        __syncthreads();
        if (t < 128)
            dec_feat[b * H_ + qq * 128 + t] = pr[t] + pr[t + 128] + pr[t + 256] + pr[t + 384]
                                              + dec_b[qq * 128 + t];
    }
}

// ================= fused MFMA GEMM (fp16) + tanh + dot(v) + 4-block sync + softmax + ctx =
// k-loop byte-identical to the 70 us baseline. After scores: per-batch arrival flag
// (store->fence->release-add; acquire-spin until 4 siblings arrive), then each block does
// the masked softmax for its batch (4x redundant, trivial) and the context partial over
// ITS OWN 128 enc rows (XCD-L2 warm, float4), LDS-reduced, one atomicAdd per h.
#define BM 128

#define STAGE_B(BUF, KS1)                                                                  \
    {                                                                                      \
        _Pragma("unroll")                                                                  \
        for (int it = 0; it < 2; ++it)                                                     \
            __builtin_amdgcn_global_load_lds(                                              \
                (const __attribute__((address_space(1))) void*)(bh16 + goffB[it] + (KS1) * 32), \
                (__attribute__((address_space(3))) void*)&Bsh[BUF][(wv * 2 + it) * 512],   \
                16, 0, 0);                                                                 \
    }

#define CVTWRITEA(BUF, A4)                                                                 \
    {                                                                                      \
        float axs[4] = {A4.x, A4.y, A4.z, A4.w};                                           \
        u16x4 hh;                                                                          \
        _Pragma("unroll")                                                                  \
        for (int j = 0; j < 4; ++j)                                                        \
            hh[j] = __builtin_bit_cast(USH, (_Float16)axs[j]);                             \
        *(u16x4*)&Ash[BUF][awoff] = hh;                                                    \
    }

__launch_bounds__(1024, 4)
__global__ void fused_score_mfma(const float* __restrict__ enc,
                                 const USH* __restrict__ bh16,
                                 const float* __restrict__ attn_b,
                                 const float* __restrict__ dec_feat,
                                 const float* __restrict__ cov_feat,
                                 const float* __restrict__ v,
                                 float* __restrict__ scores,
                                 const int* __restrict__ mask,
                                 const float* __restrict__ coverage,
                                 float* __restrict__ out,
                                 int* __restrict__ flags) {
    __shared__ USH Bsh[3][16384];      // [buf][512n x 32k swizzled fp16] = 96 KB
    __shared__ USH Ash[2][4096];       // [buf][128r x 32k swizzled fp16] = 16 KB

    const int t  = threadIdx.x;
    const int wv = t >> 6, ln = t & 63;
    const int wr = wv >> 3, wc = wv & 7;     // 2M x 8N, wave tile 64 x 64
    const int q  = ln >> 4, cl = ln & 15;
    const int m0 = blockIdx.x * BM;
    const int b  = blockIdx.x >> 2;          // 4 row-tiles per batch row
    const int lt = blockIdx.x & 3;

    int goffB[2];
    #pragma unroll
    for (int it = 0; it < 2; ++it) {
        int c   = wv * 2 + it;
        int srl = ln >> 3;
        int u   = (ln & 7) ^ (srl & 7);
        int n   = c * 16 + srl * 2 + (u >> 2);
        goffB[it] = n * 512 + (u & 3) * 8;
    }
    const int sA   = (((cl & 1) * 4 + q) ^ ((cl >> 1) & 7)) * 8;
    const int aoff = wr * 2048 + (cl >> 1) * 64 + sA;
    const int boff = wc * 2048 + (cl >> 1) * 64 + sA;

    const int arow = t >> 3, akoct = t & 7;
    const int asw  = ((arow & 1) * 4 + (akoct >> 1)) ^ ((arow >> 1) & 7);
    const int awoff = (arow >> 1) * 64 + asw * 8 + (akoct & 1) * 4;
    const float* agsrc = enc + (size_t)(m0 + arow) * H_ + akoct * 4;

    f32x4 acc[4][4];
    #pragma unroll
    for (int mf = 0; mf < 4; ++mf)
        #pragma unroll
        for (int nf = 0; nf < 4; ++nf) acc[mf][nf] = (f32x4){0.f, 0.f, 0.f, 0.f};

    float4 aP = *(const float4*)(agsrc + 32);
    float4 c0 = *(const float4*)agsrc;
    __builtin_amdgcn_sched_barrier(0);
    STAGE_B(0, 0);
    STAGE_B(1, 1);
    __builtin_amdgcn_sched_barrier(0);
    CVTWRITEA(0, c0);
    asm volatile("s_waitcnt lgkmcnt(0)" ::: "memory");
    asm volatile("s_waitcnt vmcnt(2)" ::: "memory");
    __builtin_amdgcn_sched_barrier(0);
    __builtin_amdgcn_s_barrier();

    #pragma unroll
    for (int ks = 0; ks < 16; ++ks) {
        const int curB = ks % 3;
        const int curA = ks & 1, nxtA = curA ^ 1;
        float4 aN;
        if (ks < 14) {
            STAGE_B((ks + 2) % 3, ks + 2);
            aN = *(const float4*)(agsrc + (ks + 2) * 32);
            __builtin_amdgcn_sched_barrier(0);
        }

        f16x8 ah[4];
        #pragma unroll
        for (int mf = 0; mf < 4; ++mf)
            ah[mf] = *(const f16x8*)&Ash[curA][aoff + mf * 512];
        __builtin_amdgcn_s_setprio(1);
        #pragma unroll
        for (int nf = 0; nf < 4; ++nf) {
            f16x8 bh = *(const f16x8*)&Bsh[curB][boff + nf * 512];
            #pragma unroll
            for (int mf = 0; mf < 4; ++mf)
                acc[mf][nf] = __builtin_amdgcn_mfma_f32_16x16x32_f16(ah[mf], bh, acc[mf][nf], 0, 0, 0);
        }
        __builtin_amdgcn_s_setprio(0);

        if (ks < 15) {
            CVTWRITEA(nxtA, aP);
            aP = aN;
            asm volatile("s_waitcnt lgkmcnt(0)" ::: "memory");
            if (ks < 14)
                asm volatile("s_waitcnt vmcnt(3)" ::: "memory");
            else
                asm volatile("s_waitcnt vmcnt(0)" ::: "memory");
            __builtin_amdgcn_sched_barrier(0);
            __builtin_amdgcn_s_barrier();
        }
    }
    __syncthreads();

    float (*scred)[BM] = (float (*)[BM])Ash;
    float addv[4], vvv[4];
    #pragma unroll
    for (int nf = 0; nf < 4; ++nf) {
        int n = wc * 64 + nf * 16 + cl;
        addv[nf] = attn_b[n] + dec_feat[b * H_ + n];
        vvv[nf]  = v[b * H_ + n];
    }
    #pragma unroll
    for (int mf = 0; mf < 4; ++mf) {
        #pragma unroll
        for (int reg = 0; reg < 4; ++reg) {
            int row = wr * 64 + mf * 16 + q * 4 + reg;
            float cf = cov_feat[m0 + row];
            float s = 0.f;
            #pragma unroll
            for (int nf = 0; nf < 4; ++nf)
                s += fast_tanh(acc[mf][nf][reg] + addv[nf] + cf) * vvv[nf];
            s += __shfl_xor(s, 1, 64);
            s += __shfl_xor(s, 2, 64);
            s += __shfl_xor(s, 4, 64);
            s += __shfl_xor(s, 8, 64);
            if (cl == 0) scred[wc][row] = s;
        }
    }
    __syncthreads();
    if (t < BM) {
        float s = 0.f;
        #pragma unroll
        for (int g = 0; g < 8; ++g) s += scred[g][t];
        scores[m0 + t] = s;
    }

    // ---- publish scores, arrive, and wait for the 3 sibling row-tile blocks ----------
    __threadfence();                               // drain + device-visibility for scores
    __syncthreads();
    if (t == 0) {
        __hip_atomic_fetch_add(&flags[b], 1, __ATOMIC_ACQ_REL, __HIP_MEMORY_SCOPE_AGENT);
        while (__hip_atomic_load(&flags[b], __ATOMIC_ACQUIRE, __HIP_MEMORY_SCOPE_AGENT) < 4)
            __builtin_amdgcn_s_sleep(1);
    }
    __syncthreads();
    __threadfence();                               // acquire: invalidate stale cache lines

    // ---- phase 2: masked softmax over scores[b,:] (4x redundant per batch, trivial) ----
    float* wsm    = (float*)&Bsh[0][0];    // [512] attn weights for batch b
    float* red16  = wsm + 512;             // [16]
    float* red16b = wsm + 544;             // [16]
    float sv = 0.f; bool mk = false;
    if (t < 512) { mk = (mask[b * L_ + t] == 1); sv = scores[b * L_ + t]; }
    float val = (t < 512 && mk) ? sv : -INFINITY;
    float r = val;
    #pragma unroll
    for (int d = 1; d <= 32; d <<= 1) r = fmaxf(r, __shfl_xor(r, d, 64));
    if (ln == 0) red16[wv] = r;
    __syncthreads();
    float gmax = red16[0];
    #pragma unroll
    for (int i = 1; i < 16; ++i) gmax = fmaxf(gmax, red16[i]);
    float p = (t < 512 && mk) ? __expf(sv - gmax) : 0.f;
    float qq = p;
    #pragma unroll
    for (int d = 1; d <= 32; d <<= 1) qq += __shfl_xor(qq, d, 64);
    if (ln == 0) red16b[wv] = qq;
    __syncthreads();
    float tot = 0.f;
    #pragma unroll
    for (int i = 0; i < 16; ++i) tot += red16b[i];
    float wt = p / tot;
    if (t < 512) {
        wsm[t] = wt;
        if (lt == 0) {
            out[B_ * H_ + b * L_ + t] = wt;                             // attn_weights
            out[B_ * H_ + B_ * L_ + b * L_ + t] = coverage[b * L_ + t] + wt; // new_coverage
        }
    }
    __syncthreads();

    // ---- phase 3: context partial over THIS block's 128 enc rows (L2-warm), float4 ----
    {
        const int h4 = t & 127, rg = t >> 7;   // 128 float4 columns x 8 row-groups
        const float4* ebase = (const float4*)enc
                              + ((size_t)(b * 512 + lt * 128 + rg * 16)) * 128 + h4;
        const float* wloc = wsm + lt * 128 + rg * 16;
        float4 a4 = {0.f, 0.f, 0.f, 0.f};
        #pragma unroll
        for (int k = 0; k < 16; ++k) {
            float wl_ = wloc[k];
            float4 e = ebase[(size_t)k * 128];
            a4.x += wl_ * e.x; a4.y += wl_ * e.y; a4.z += wl_ * e.z; a4.w += wl_ * e.w;
        }
        ((float4*)Ash)[rg * 128 + h4] = a4;    // 8 x 512 floats = 16 KB, fits Ash exactly
        __syncthreads();
        if (t < 512) {
            const float* Ar = (const float*)Ash;
            float csum = 0.f;
            #pragma unroll
            for (int g = 0; g < 8; ++g) csum += Ar[g * 512 + t];
            atomicAdd(&out[b * H_ + t], csum);
        }
    }
}

extern "C" void kernel_launch(void* const* d_in, const int* in_sizes, int n_in,
                              void* d_out, int out_size, void* d_ws, size_t ws_size,
                              hipStream_t stream) {
    const float* enc      = (const float*)d_in[0];
    const int*   mask     = (const int*)d_in[1];
    const float* hidden   = (const float*)d_in[2];
    const float* coverage = (const float*)d_in[3];
    const float* attn_w   = (const float*)d_in[4];
    const float* attn_b   = (const float*)d_in[5];
    const float* dec_w    = (const float*)d_in[6];
    const float* dec_b    = (const float*)d_in[7];
    const float* cvg_w    = (const float*)d_in[8];
    const float* cvg_b    = (const float*)d_in[9];
    const float* v        = (const float*)d_in[10];
    float* out = (float*)d_out;
    float* ws  = (float*)d_ws;
    float* scores   = ws;
    float* dec_feat = ws + 32768;
    float* cov_feat = ws + 65536;
    int*   flags    = (int*)(ws + 98304);
    USH* bpk = (USH*)(ws + 360448);

    hipLaunchKernelGGL(pre_kernel, dim3(896), dim3(512), 0, stream,
                       cvg_w, cvg_b, coverage, attn_w, bpk, hidden, dec_w, dec_b,
                       dec_feat, cov_feat, flags, out);

    hipLaunchKernelGGL(fused_score_mfma, dim3(256), dim3(1024), 0, stream,
                       enc, bpk, attn_b, dec_feat, cov_feat, v, scores, mask,
                       coverage, out, flags);
}

// Round 3
// 67.714 us; speedup vs baseline: 2.7854x; 2.7854x over previous
//
#include <hip/hip_runtime.h>

#define B_ 64
#define L_ 512
#define H_ 512
#define CENTER 255

typedef float  f32x4  __attribute__((ext_vector_type(4)));
typedef _Float16 f16x8 __attribute__((ext_vector_type(8)));
typedef unsigned short u16x4 __attribute__((ext_vector_type(4)));
typedef unsigned short USH;

// ws layout (floats):
//   scores   [0,      32768)
//   dec_feat [32768,  65536)
//   cov_feat [65536,  98304)
//   Bpk     [360448, 491520)   ushort[512][512]: fp16(attn_w) bits (row-major n,k)

__device__ __forceinline__ float fast_tanh(float x) {
    float e = __expf(2.0f * x);
    return 1.0f - 2.0f * __builtin_amdgcn_rcpf(e + 1.0f);
}

// ================= pre: cov-direct (0..511) + conv_b (512..639) + dec (640..895) ========
__launch_bounds__(512)
__global__ void pre_kernel(const float* __restrict__ cvg_w, const float* __restrict__ cvg_b,
                           const float* __restrict__ coverage,
                           const float* __restrict__ aw, USH* __restrict__ bh16,
                           const float* __restrict__ hidden, const float* __restrict__ dec_w,
                           const float* __restrict__ dec_b,
                           float* __restrict__ dec_feat, float* __restrict__ cov_feat) {
    __shared__ float pool[34304];      // role A: wl[512] + cs[512][65]; role C: sbuf+pr
    const int bid = blockIdx.x, t = threadIdx.x;
    if (bid < 512) {
        float* wl = pool;                          // [512]
        float* cs = pool + 512;                    // [j][c] = [512][65]
        const int i = bid;
        wl[t] = cvg_w[((size_t)(i * L_ + t)) * H_ + CENTER];   // 1 scattered line/thread
        #pragma unroll 8
        for (int c = 0; c < 64; ++c)
            cs[t * 65 + c] = coverage[c * L_ + t];             // coalesced; write 2/bank
        __syncthreads();
        const int b = t >> 3, jg = t & 7;
        float sum = 0.f;
        #pragma unroll 8
        for (int jj = 0; jj < 64; ++jj) {
            int j = jg * 64 + ((jj + jg * 8) & 63);            // rotation: read 2/bank
            sum += cs[j * 65 + b] * wl[j];
        }
        sum += __shfl_xor(sum, 1, 64);
        sum += __shfl_xor(sum, 2, 64);
        sum += __shfl_xor(sum, 4, 64);
        if (jg == 0) cov_feat[b * L_ + i] = sum + cvg_b[i];
    } else if (bid < 640) {
        int i = (bid - 512) * 512 + t;             // float4 per thread
        float4 x = *(const float4*)&aw[(size_t)i * 4];
        float xs[4] = {x.x, x.y, x.z, x.w};
        u16x4 h;
        #pragma unroll
        for (int j = 0; j < 4; ++j)
            h[j] = __builtin_bit_cast(USH, (_Float16)xs[j]);
        *(u16x4*)&bh16[(size_t)i * 4] = h;
    } else {
        float* sbuf = pool;                        // [512]
        float* pr   = pool + 512;                  // [512]
        const int blk = bid - 640, b = blk >> 2, qq = blk & 3;
        const int ol = t & 127, part = t >> 7;
        sbuf[t] = hidden[b * H_ + t];
        __syncthreads();
        const float* row  = dec_w + (size_t)(qq * 128 + ol) * H_ + part * 128;
        const float* hseg = sbuf + part * 128;
        float d0 = 0.f, d1 = 0.f, d2 = 0.f, d3 = 0.f;
        #pragma unroll
        for (int k = 0; k < 128; k += 16) {
            float4 w0 = *(const float4*)&row[k];
            float4 w1 = *(const float4*)&row[k + 4];
            float4 w2 = *(const float4*)&row[k + 8];
            float4 w3 = *(const float4*)&row[k + 12];
            d0 += w0.x * hseg[k]      + w0.y * hseg[k + 1]  + w0.z * hseg[k + 2]  + w0.w * hseg[k + 3];
            d1 += w1.x * hseg[k + 4]  + w1.y * hseg[k + 5]  + w1.z * hseg[k + 6]  + w1.w * hseg[k + 7];
            d2 += w2.x * hseg[k + 8]  + w2.y * hseg[k + 9]  + w2.z * hseg[k + 10] + w2.w * hseg[k + 11];
            d3 += w3.x * hseg[k + 12] + w3.y * hseg[k + 13] + w3.z * hseg[k + 14] + w3.w * hseg[k + 15];
        }
        pr[t] = d0 + d1 + d2 + d3;
        __syncthreads();
        if (t < 128)
            dec_feat[b * H_ + qq * 128 + t] = pr[t] + pr[t + 128] + pr[t + 256] + pr[t + 384]
                                              + dec_b[qq * 128 + t];
    }
}

// ================= fused MFMA GEMM (fp16) + tanh + dot(v) -> scores =====================
// (byte-identical to the 70 us baseline: BM=128, grid 256, 16 waves 2Mx8N, B triple-
//  buffered depth-2, A reg-prefetch depth-2 + LDS dbuf, ONE barrier/step, counted vmcnt(3).)
#define BM 128

#define STAGE_B(BUF, KS1)                                                                  \
    {                                                                                      \
        _Pragma("unroll")                                                                  \
        for (int it = 0; it < 2; ++it)                                                     \
            __builtin_amdgcn_global_load_lds(                                              \
                (const __attribute__((address_space(1))) void*)(bh16 + goffB[it] + (KS1) * 32), \
                (__attribute__((address_space(3))) void*)&Bsh[BUF][(wv * 2 + it) * 512],   \
                16, 0, 0);                                                                 \
    }

#define CVTWRITEA(BUF, A4)                                                                 \
    {                                                                                      \
        float axs[4] = {A4.x, A4.y, A4.z, A4.w};                                           \
        u16x4 hh;                                                                          \
        _Pragma("unroll")                                                                  \
        for (int j = 0; j < 4; ++j)                                                        \
            hh[j] = __builtin_bit_cast(USH, (_Float16)axs[j]);                             \
        *(u16x4*)&Ash[BUF][awoff] = hh;                                                    \
    }

__launch_bounds__(1024, 4)
__global__ void fused_score_mfma(const float* __restrict__ enc,
                                 const USH* __restrict__ bh16,
                                 const float* __restrict__ attn_b,
                                 const float* __restrict__ dec_feat,
                                 const float* __restrict__ cov_feat,
                                 const float* __restrict__ v,
                                 float* __restrict__ scores) {
    __shared__ USH Bsh[3][16384];      // [buf][512n x 32k swizzled fp16] = 96 KB
    __shared__ USH Ash[2][4096];       // [buf][128r x 32k swizzled fp16] = 16 KB

    const int t  = threadIdx.x;
    const int wv = t >> 6, ln = t & 63;
    const int wr = wv >> 3, wc = wv & 7;     // 2M x 8N, wave tile 64 x 64
    const int q  = ln >> 4, cl = ln & 15;
    const int m0 = blockIdx.x * BM;
    const int b  = blockIdx.x >> 2;          // 4 row-tiles per batch row

    int goffB[2];
    #pragma unroll
    for (int it = 0; it < 2; ++it) {
        int c   = wv * 2 + it;
        int srl = ln >> 3;
        int u   = (ln & 7) ^ (srl & 7);
        int n   = c * 16 + srl * 2 + (u >> 2);
        goffB[it] = n * 512 + (u & 3) * 8;
    }
    const int sA   = (((cl & 1) * 4 + q) ^ ((cl >> 1) & 7)) * 8;
    const int aoff = wr * 2048 + (cl >> 1) * 64 + sA;
    const int boff = wc * 2048 + (cl >> 1) * 64 + sA;

    const int arow = t >> 3, akoct = t & 7;
    const int asw  = ((arow & 1) * 4 + (akoct >> 1)) ^ ((arow >> 1) & 7);
    const int awoff = (arow >> 1) * 64 + asw * 8 + (akoct & 1) * 4;
    const float* agsrc = enc + (size_t)(m0 + arow) * H_ + akoct * 4;

    f32x4 acc[4][4];
    #pragma unroll
    for (int mf = 0; mf < 4; ++mf)
        #pragma unroll
        for (int nf = 0; nf < 4; ++nf) acc[mf][nf] = (f32x4){0.f, 0.f, 0.f, 0.f};

    float4 aP = *(const float4*)(agsrc + 32);
    float4 c0 = *(const float4*)agsrc;
    __builtin_amdgcn_sched_barrier(0);
    STAGE_B(0, 0);
    STAGE_B(1, 1);
    __builtin_amdgcn_sched_barrier(0);
    CVTWRITEA(0, c0);
    asm volatile("s_waitcnt lgkmcnt(0)" ::: "memory");
    asm volatile("s_waitcnt vmcnt(2)" ::: "memory");
    __builtin_amdgcn_sched_barrier(0);
    __builtin_amdgcn_s_barrier();

    #pragma unroll
    for (int ks = 0; ks < 16; ++ks) {
        const int curB = ks % 3;
        const int curA = ks & 1, nxtA = curA ^ 1;
        float4 aN;
        if (ks < 14) {
            STAGE_B((ks + 2) % 3, ks + 2);
            aN = *(const float4*)(agsrc + (ks + 2) * 32);
            __builtin_amdgcn_sched_barrier(0);
        }

        f16x8 ah[4];
        #pragma unroll
        for (int mf = 0; mf < 4; ++mf)
            ah[mf] = *(const f16x8*)&Ash[curA][aoff + mf * 512];
        __builtin_amdgcn_s_setprio(1);
        #pragma unroll
        for (int nf = 0; nf < 4; ++nf) {
            f16x8 bh = *(const f16x8*)&Bsh[curB][boff + nf * 512];
            #pragma unroll
            for (int mf = 0; mf < 4; ++mf)
                acc[mf][nf] = __builtin_amdgcn_mfma_f32_16x16x32_f16(ah[mf], bh, acc[mf][nf], 0, 0, 0);
        }
        __builtin_amdgcn_s_setprio(0);

        if (ks < 15) {
            CVTWRITEA(nxtA, aP);
            aP = aN;
            asm volatile("s_waitcnt lgkmcnt(0)" ::: "memory");
            if (ks < 14)
                asm volatile("s_waitcnt vmcnt(3)" ::: "memory");
            else
                asm volatile("s_waitcnt vmcnt(0)" ::: "memory");
            __builtin_amdgcn_sched_barrier(0);
            __builtin_amdgcn_s_barrier();
        }
    }
    __syncthreads();

    float (*scred)[BM] = (float (*)[BM])Ash;
    float addv[4], vvv[4];
    #pragma unroll
    for (int nf = 0; nf < 4; ++nf) {
        int n = wc * 64 + nf * 16 + cl;
        addv[nf] = attn_b[n] + dec_feat[b * H_ + n];
        vvv[nf]  = v[b * H_ + n];
    }
    #pragma unroll
    for (int mf = 0; mf < 4; ++mf) {
        #pragma unroll
        for (int reg = 0; reg < 4; ++reg) {
            int row = wr * 64 + mf * 16 + q * 4 + reg;
            float cf = cov_feat[m0 + row];
            float s = 0.f;
            #pragma unroll
            for (int nf = 0; nf < 4; ++nf)
                s += fast_tanh(acc[mf][nf][reg] + addv[nf] + cf) * vvv[nf];
            s += __shfl_xor(s, 1, 64);
            s += __shfl_xor(s, 2, 64);
            s += __shfl_xor(s, 4, 64);
            s += __shfl_xor(s, 8, 64);
            if (cl == 0) scred[wc][row] = s;
        }
    }
    __syncthreads();
    if (t < BM) {
        float s = 0.f;
        #pragma unroll
        for (int g = 0; g < 8; ++g) s += scred[g][t];
        scores[m0 + t] = s;
    }
}

// ================= smctx: masked softmax + outputs + context ============================
// v2: 1024 threads (16 waves/CU, 2x TLP) + float4 enc loads (4x fewer VMEM instrs).
// Thread (rg = t>>5, c4 = t&31): rows rg+32k (k=0..15), one float4 per row at column
// hc*32+c4 -> per-rg 512B contiguous coalesced. LDS partial [32][32] float4, 32-thread
// final sum -> float4 store.
__launch_bounds__(1024)
__global__ void smctx_kernel(const float* __restrict__ scores, const int* __restrict__ mask,
                             const float* __restrict__ coverage, const float* __restrict__ enc,
                             float* __restrict__ out) {
    __shared__ float w[512];
    __shared__ float red[16];
    __shared__ float red2[16];
    __shared__ float4 cred4[32][32];   // 16 KB
    const int bid = blockIdx.x, b = bid >> 2, hc = bid & 3, t = threadIdx.x;
    const int wv = t >> 6, ln = t & 63;

    float sv = 0.f; bool mk = false;
    if (t < 512) {
        mk = (mask[b * L_ + t] == 1);
        sv = scores[b * L_ + t];
    }
    float val = (t < 512 && mk) ? sv : -INFINITY;

    float r = val;
    #pragma unroll
    for (int d = 1; d <= 32; d <<= 1) r = fmaxf(r, __shfl_xor(r, d, 64));
    if (ln == 0) red[wv] = r;
    __syncthreads();
    float gmax = red[0];
    #pragma unroll
    for (int i = 1; i < 16; ++i) gmax = fmaxf(gmax, red[i]);

    float p = (t < 512 && mk) ? __expf(sv - gmax) : 0.f;
    float qq = p;
    #pragma unroll
    for (int d = 1; d <= 32; d <<= 1) qq += __shfl_xor(qq, d, 64);
    if (ln == 0) red2[wv] = qq;
    __syncthreads();
    float tot = 0.f;
    #pragma unroll
    for (int i = 0; i < 16; ++i) tot += red2[i];

    float wt = p / tot;
    if (t < 512) {
        w[t] = wt;
        if (hc == 0) {
            out[B_ * H_ + b * L_ + t] = wt;                                   // attn_weights
            out[B_ * H_ + B_ * L_ + b * L_ + t] = coverage[b * L_ + t] + wt;  // new_coverage
        }
    }
    __syncthreads();

    const int c4 = t & 31, rg = t >> 5;    // 32 row-groups x 32 float4 columns
    const float4* ebase = (const float4*)enc
                          + ((size_t)(b * L_ + rg)) * 128 + hc * 32 + c4;
    float4 a4 = {0.f, 0.f, 0.f, 0.f};
    #pragma unroll
    for (int k = 0; k < 16; ++k) {         // rows rg, rg+32, ..., rg+480
        float wl_ = w[rg + 32 * k];
        float4 e = ebase[(size_t)(32 * k) * 128];
        a4.x += wl_ * e.x; a4.y += wl_ * e.y; a4.z += wl_ * e.z; a4.w += wl_ * e.w;
    }
    cred4[rg][c4] = a4;
    __syncthreads();
    if (t < 32) {
        float4 s = {0.f, 0.f, 0.f, 0.f};
        #pragma unroll
        for (int g = 0; g < 32; ++g) {
            float4 c = cred4[g][t];
            s.x += c.x; s.y += c.y; s.z += c.z; s.w += c.w;
        }
        *(float4*)&out[b * H_ + hc * 128 + t * 4] = s;
    }
}

extern "C" void kernel_launch(void* const* d_in, const int* in_sizes, int n_in,
                              void* d_out, int out_size, void* d_ws, size_t ws_size,
                              hipStream_t stream) {
    const float* enc      = (const float*)d_in[0];
    const int*   mask     = (const int*)d_in[1];
    const float* hidden   = (const float*)d_in[2];
    const float* coverage = (const float*)d_in[3];
    const float* attn_w   = (const float*)d_in[4];
    const float* attn_b   = (const float*)d_in[5];
    const float* dec_w    = (const float*)d_in[6];
    const float* dec_b    = (const float*)d_in[7];
    const float* cvg_w    = (const float*)d_in[8];
    const float* cvg_b    = (const float*)d_in[9];
    const float* v        = (const float*)d_in[10];
    float* out = (float*)d_out;
    float* ws  = (float*)d_ws;
    float* scores   = ws;
    float* dec_feat = ws + 32768;
    float* cov_feat = ws + 65536;
    USH* bpk = (USH*)(ws + 360448);

    hipLaunchKernelGGL(pre_kernel,       dim3(896),  dim3(512),  0, stream,
                       cvg_w, cvg_b, coverage, attn_w, bpk, hidden, dec_w, dec_b,
                       dec_feat, cov_feat);
    hipLaunchKernelGGL(fused_score_mfma, dim3(256),  dim3(1024), 0, stream,
                       enc, bpk, attn_b, dec_feat, cov_feat, v, scores);
    hipLaunchKernelGGL(smctx_kernel,     dim3(256),  dim3(1024), 0, stream,
                       scores, mask, coverage, enc, out);
}